// Round 5
// baseline (24.673 us; speedup 1.0000x reference)
//
#include <hip/hip_runtime.h>

#define RADIUS 5
#define WIN    11
#define WIN2   121
#define KCLS   6
#define HH     128
#define WW     128
#define BB     4
#define NPIX   (HH*WW)
#define TPB    512                  // 8 lanes per pixel, 64 px (half row)
#define NBLK   (BB*HH*2)            // 1024 blocks
#define PXB    64                   // pixels per block
#define LABW   (PXB + 2*RADIUS)     // 74 cols
#define LABPL  (WIN*LABW)           // 814 floats per class plane
#define LABSZ  (KCLS*LABPL)         // 4884 floats = 19.5 KB

__global__ __launch_bounds__(TPB, 8) void ncut_main(
    const float* __restrict__ labels,
    const float* __restrict__ weights,
    float* __restrict__ part) {
  __shared__ float shl[LABSZ];      // zero-padded label tile, K x 11 x 74
  __shared__ int   shtab[128];      // o -> oy*LABW+ox
  __shared__ float shred[8 * 12];   // per-wave partials

  const int tid  = threadIdx.x;
  const int blk  = blockIdx.x;
  const int b    = blk >> 8;                // 256 blocks per image
  const int rem  = blk & 255;
  const int y0   = rem >> 1;
  const int x0   = (rem & 1) * PXB;

  if (tid < WIN2) shtab[tid] = (tid / WIN) * LABW + (tid % WIN);

  // ---- stage zero-padded label tile ----
  const float* labB = labels + (size_t)b * KCLS * NPIX;
  for (int idx = tid; idx < LABSZ; idx += TPB) {
    int k  = idx / LABPL;
    int rm = idx - k * LABPL;
    int tr = rm / LABW;
    int tc = rm - tr * LABW;
    int gy = y0 - RADIUS + tr;
    int gx = x0 + tc - RADIUS;
    float v = 0.0f;
    if ((unsigned)gy < (unsigned)HH && (unsigned)gx < (unsigned)WW)
      v = labB[((size_t)k * HH + gy) * WW + gx];
    shl[idx] = v;
  }
  __syncthreads();

  // ---- per-thread: pixel px, tap set o = 8j + q ----
  const int px = tid >> 3;          // 0..63
  const int q  = tid & 7;           // 0..7
  // per-instruction: 8 q-lanes read 8 CONSECUTIVE dwords (32B run)
  const float* wrowq = weights +
      ((size_t)b * NPIX + (size_t)y0 * WW + x0 + px) * WIN2 + q;

  float wp[KCLS] = {0.f, 0.f, 0.f, 0.f, 0.f, 0.f};
  float wsum = 0.f;

#pragma unroll 5
  for (int j = 0; j < 15; ++j) {
    const float w = wrowq[8 * j];           // tap o = 8j + q
    wsum += w;
    const int li = px + shtab[8 * j + q];   // consecutive sites -> no conflict
#pragma unroll
    for (int k = 0; k < KCLS; ++k)
      wp[k] += w * shl[li + k * LABPL];
  }
  if (q == 0) {                     // tail: o = 120
    const float w = wrowq[120];
    wsum += w;
    const int li = px + shtab[120];
#pragma unroll
    for (int k = 0; k < KCLS; ++k)
      wp[k] += w * shl[li + k * LABPL];
  }

  // ---- reduce across the 8 q-lanes (adjacent lanes) ----
#pragma unroll
  for (int off = 1; off <= 4; off <<= 1) {
    wsum += __shfl_xor(wsum, off);
#pragma unroll
    for (int k = 0; k < KCLS; ++k) wp[k] += __shfl_xor(wp[k], off);
  }

  // ---- num/den per pixel (all 8 q-lanes hold identical values) ----
  const int ce = px + RADIUS * LABW + RADIUS;   // center offset
  float nv[KCLS], dv[KCLS];
#pragma unroll
  for (int k = 0; k < KCLS; ++k) {
    const float p = shl[ce + k * LABPL];
    nv[k] = p * wp[k];
    dv[k] = p * wsum;
  }

  // ---- reduce across the 8 pixels of this wave (lane bits 3..5) ----
#pragma unroll
  for (int off = 8; off <= 32; off <<= 1) {
#pragma unroll
    for (int k = 0; k < KCLS; ++k) {
      nv[k] += __shfl_xor(nv[k], off);
      dv[k] += __shfl_xor(dv[k], off);
    }
  }
  const int wave = tid >> 6;
  if ((tid & 63) == 0) {
#pragma unroll
    for (int k = 0; k < KCLS; ++k) {
      shred[wave * 12 + k]     = nv[k];
      shred[wave * 12 + 6 + k] = dv[k];
    }
  }
  __syncthreads();
  if (tid < 12) {
    float s = 0.f;
#pragma unroll
    for (int w = 0; w < 8; ++w) s += shred[w * 12 + tid];
    part[blk * 12 + tid] = s;
  }
}

// ---- final: L = num/den per (b,k); out = K - (1/B) * sum |L| ----
// 8 segments x 32 (b,k)-slots, 32 block-partials each, LDS reduce.
__global__ __launch_bounds__(256) void ncut_final(
    const float* __restrict__ part, float* __restrict__ out) {
  __shared__ float shf[8 * 48];
  const int t   = threadIdx.x;
  const int seg = t >> 5;           // 0..7
  const int bk  = t & 31;           // 0..31, active < 24
  if (bk < 24) {
    const int b = bk / KCLS;
    const int k = bk - b * KCLS;
    const int r0 = b * 256 + seg * 32;
    float num = 0.f, den = 0.f;
#pragma unroll 4
    for (int i = 0; i < 32; ++i) {
      const float* p = part + (size_t)(r0 + i) * 12;
      num += p[k];
      den += p[6 + k];
    }
    shf[seg * 48 + bk * 2]     = num;
    shf[seg * 48 + bk * 2 + 1] = den;
  }
  __syncthreads();
  float val = 0.f;
  if (t < 24) {
    float n = 0.f, d = 0.f;
#pragma unroll
    for (int s = 0; s < 8; ++s) {
      n += shf[s * 48 + t * 2];
      d += shf[s * 48 + t * 2 + 1];
    }
    val = fabsf(n / d) * (1.0f / BB);
  }
  if (t < 64) {
#pragma unroll
    for (int off = 16; off; off >>= 1) val += __shfl_down(val, off);
    if (t == 0) out[0] = (float)KCLS - val;
  }
}

extern "C" void kernel_launch(void* const* d_in, const int* in_sizes, int n_in,
                              void* d_out, int out_size, void* d_ws, size_t ws_size,
                              hipStream_t stream) {
  const float* labels  = (const float*)d_in[0];
  const float* weights = (const float*)d_in[1];
  float* out  = (float*)d_out;
  float* part = (float*)d_ws;      // 1024 blocks * 12 floats = 49152 B

  ncut_main<<<NBLK, TPB, 0, stream>>>(labels, weights, part);
  ncut_final<<<1, 256, 0, stream>>>(part, out);
}

// Round 6
// 22.287 us; speedup vs baseline: 1.1070x; 1.1070x over previous
//
#include <hip/hip_runtime.h>

#define RADIUS 5
#define WIN    11
#define WIN2   121
#define KCLS   6
#define HH     128
#define WW     128
#define BB     4
#define NPIX   (HH*WW)
#define TPB    256                  // 2 lanes per pixel, 128 px = one row
#define NBLK   (BB*HH)              // 512 blocks
#define LABW   138                  // cols -5..132
#define NSITE  (WIN*LABW)           // 1518 sites (11 rows x 138 cols)
#define PLSTR  (NSITE*2)            // floats per class-pair plane

__global__ __launch_bounds__(TPB, 2) void ncut_main(
    const float* __restrict__ labels,
    const float* __restrict__ weights,
    float* __restrict__ part) {
  // label tile: 3 pair-planes of [site][2 classes] -> ds_read_b64 per pair
  __shared__ float shl[3 * PLSTR];    // 9108 floats = 36.4 KB
  __shared__ float shred[4 * 12];

  const int tid = threadIdx.x;
  const int blk = blockIdx.x;
  const int b   = blk >> 7;
  const int y0  = blk & (HH - 1);

  // ---- stage zero-padded label tile, class-pair interleaved ----
  const float* labB = labels + (size_t)b * KCLS * NPIX;
  for (int s = tid; s < NSITE; s += TPB) {
    const int tr = s / LABW;
    const int tc = s - tr * LABW;
    const int gy = y0 - RADIUS + tr;
    const int gx = tc - RADIUS;
    const bool ok = ((unsigned)gy < (unsigned)HH) & ((unsigned)gx < (unsigned)WW);
    const float* lp = labB + (size_t)gy * WW + gx;
#pragma unroll
    for (int p = 0; p < 3; ++p) {
      float2 v = make_float2(0.f, 0.f);
      if (ok) {
        v.x = lp[(size_t)(2 * p) * NPIX];
        v.y = lp[(size_t)(2 * p + 1) * NPIX];
      }
      *reinterpret_cast<float2*>(shl + p * PLSTR + 2 * s) = v;  // 8B-aligned
    }
  }
  __syncthreads();

  // ---- per-thread: pixel px, half-window q (taps q*60 .. q*60+59, +120 for q=0)
  const int px = tid >> 1;          // x coordinate, 0..127
  const int q  = tid & 1;
  const float* wr = weights +
      ((size_t)b * NPIX + (size_t)y0 * WW + px) * WIN2 + q * 60;

  float2 a0 = make_float2(0.f, 0.f);
  float2 a1 = make_float2(0.f, 0.f);
  float2 a2 = make_float2(0.f, 0.f);
  float wsum = 0.f;

#pragma unroll
  for (int g = 0; g < 15; ++g) {
    float4 wv;
    __builtin_memcpy(&wv, wr + 4 * g, 16);   // align-4 safe vector load
#pragma unroll
    for (int m = 0; m < 4; ++m) {
      const int c  = 4 * g + m;                                  // 0..59
      const int liA = (c / WIN) * LABW + (c % WIN);              // q==0 tap c
      const int liB = ((60 + c) / WIN) * LABW + ((60 + c) % WIN);// q==1 tap 60+c
      const int li  = px + (q ? liB : liA);
      const float w = (m == 0) ? wv.x : (m == 1) ? wv.y : (m == 2) ? wv.z : wv.w;
      wsum += w;
      const float2 v0 = *reinterpret_cast<const float2*>(shl + 0 * PLSTR + 2 * li);
      const float2 v1 = *reinterpret_cast<const float2*>(shl + 1 * PLSTR + 2 * li);
      const float2 v2 = *reinterpret_cast<const float2*>(shl + 2 * PLSTR + 2 * li);
      a0.x += w * v0.x; a0.y += w * v0.y;
      a1.x += w * v1.x; a1.y += w * v1.y;
      a2.x += w * v2.x; a2.y += w * v2.y;
    }
  }
  if (q == 0) {                      // tail tap o = 120
    const float w = wr[120];
    const int li = px + 10 * LABW + 10;
    wsum += w;
    const float2 v0 = *reinterpret_cast<const float2*>(shl + 0 * PLSTR + 2 * li);
    const float2 v1 = *reinterpret_cast<const float2*>(shl + 1 * PLSTR + 2 * li);
    const float2 v2 = *reinterpret_cast<const float2*>(shl + 2 * PLSTR + 2 * li);
    a0.x += w * v0.x; a0.y += w * v0.y;
    a1.x += w * v1.x; a1.y += w * v1.y;
    a2.x += w * v2.x; a2.y += w * v2.y;
  }

  // ---- reduce the 2 q-lanes (xor 1) ----
  wsum += __shfl_xor(wsum, 1);
  a0.x += __shfl_xor(a0.x, 1); a0.y += __shfl_xor(a0.y, 1);
  a1.x += __shfl_xor(a1.x, 1); a1.y += __shfl_xor(a1.y, 1);
  a2.x += __shfl_xor(a2.x, 1); a2.y += __shfl_xor(a2.y, 1);

  // ---- num/den per pixel (center site = 5*138 + 5) ----
  const int lc = px + 5 * LABW + 5;
  const float2 c0 = *reinterpret_cast<const float2*>(shl + 0 * PLSTR + 2 * lc);
  const float2 c1 = *reinterpret_cast<const float2*>(shl + 1 * PLSTR + 2 * lc);
  const float2 c2 = *reinterpret_cast<const float2*>(shl + 2 * PLSTR + 2 * lc);
  float nv[KCLS] = {c0.x * a0.x, c0.y * a0.y, c1.x * a1.x,
                    c1.y * a1.y, c2.x * a2.x, c2.y * a2.y};
  float dv[KCLS] = {c0.x * wsum, c0.y * wsum, c1.x * wsum,
                    c1.y * wsum, c2.x * wsum, c2.y * wsum};

  // ---- reduce across the 32 pixels of this wave (lane bits 1..5) ----
#pragma unroll
  for (int off = 2; off <= 32; off <<= 1) {
#pragma unroll
    for (int k = 0; k < KCLS; ++k) {
      nv[k] += __shfl_xor(nv[k], off);
      dv[k] += __shfl_xor(dv[k], off);
    }
  }
  const int wave = tid >> 6;
  if ((tid & 63) == 0) {
#pragma unroll
    for (int k = 0; k < KCLS; ++k) {
      shred[wave * 12 + k]     = nv[k];
      shred[wave * 12 + 6 + k] = dv[k];
    }
  }
  __syncthreads();
  if (tid < 12) {
    float s = 0.f;
#pragma unroll
    for (int w = 0; w < 4; ++w) s += shred[w * 12 + tid];
    part[blk * 12 + tid] = s;
  }
}

// ---- final: L = num/den per (b,k); out = K - (1/B) * sum |L| ----
__global__ __launch_bounds__(256) void ncut_final(
    const float* __restrict__ part, float* __restrict__ out) {
  __shared__ float shf[8 * 48];
  const int t   = threadIdx.x;
  const int seg = t >> 5;           // 0..7
  const int bk  = t & 31;           // active < 24
  if (bk < 24) {
    const int b = bk / KCLS;
    const int k = bk - b * KCLS;
    const int r0 = b * HH + seg * 16;
    float num = 0.f, den = 0.f;
#pragma unroll 4
    for (int i = 0; i < 16; ++i) {
      const float* p = part + (size_t)(r0 + i) * 12;
      num += p[k];
      den += p[6 + k];
    }
    shf[seg * 48 + bk * 2]     = num;
    shf[seg * 48 + bk * 2 + 1] = den;
  }
  __syncthreads();
  float val = 0.f;
  if (t < 24) {
    float n = 0.f, d = 0.f;
#pragma unroll
    for (int s = 0; s < 8; ++s) {
      n += shf[s * 48 + t * 2];
      d += shf[s * 48 + t * 2 + 1];
    }
    val = fabsf(n / d) * (1.0f / BB);
  }
  if (t < 64) {
#pragma unroll
    for (int off = 16; off; off >>= 1) val += __shfl_down(val, off);
    if (t == 0) out[0] = (float)KCLS - val;
  }
}

extern "C" void kernel_launch(void* const* d_in, const int* in_sizes, int n_in,
                              void* d_out, int out_size, void* d_ws, size_t ws_size,
                              hipStream_t stream) {
  const float* labels  = (const float*)d_in[0];
  const float* weights = (const float*)d_in[1];
  float* out  = (float*)d_out;
  float* part = (float*)d_ws;      // 512 blocks * 12 floats = 24576 B

  ncut_main<<<NBLK, TPB, 0, stream>>>(labels, weights, part);
  ncut_final<<<1, 256, 0, stream>>>(part, out);
}

// Round 7
// 20.182 us; speedup vs baseline: 1.2225x; 1.1043x over previous
//
#include <hip/hip_runtime.h>

#define RADIUS 5
#define WIN    11
#define WIN2   121
#define KCLS   6
#define HH     128
#define WW     128
#define BB     4
#define NPIX   (HH*WW)
#define TPB    256                  // 4 lanes per pixel, 64 px (half row)
#define NBLK   (BB*HH*2)            // 1024 blocks
#define PXB    64                   // pixels per block
#define LABW   (PXB + 2*RADIUS)     // 74 cols
#define NSITE  (WIN*LABW)           // 814 sites
#define PLSTR  (NSITE*2)            // floats per class-pair plane

__global__ __launch_bounds__(TPB, 4) void ncut_main(
    const float* __restrict__ labels,
    const float* __restrict__ weights,
    float* __restrict__ part) {
  // label tile: 3 pair-planes of [site][2 classes] -> ds_read_b64 per pair
  __shared__ float shl[3 * PLSTR];    // 4884 floats = 19.5 KB
  __shared__ float shred[4 * 12];

  const int tid = threadIdx.x;
  const int blk = blockIdx.x;
  const int b   = blk >> 8;                 // 256 blocks per image
  const int rem = blk & 255;
  const int y0  = rem >> 1;
  const int x0  = (rem & 1) * PXB;

  // ---- stage zero-padded label tile, class-pair interleaved ----
  const float* labB = labels + (size_t)b * KCLS * NPIX;
  for (int s = tid; s < NSITE; s += TPB) {
    const int tr = s / LABW;
    const int tc = s - tr * LABW;
    const int gy = y0 - RADIUS + tr;
    const int gx = x0 + tc - RADIUS;
    const bool ok = ((unsigned)gy < (unsigned)HH) & ((unsigned)gx < (unsigned)WW);
    const float* lp = labB + (size_t)gy * WW + gx;
#pragma unroll
    for (int p = 0; p < 3; ++p) {
      float2 v = make_float2(0.f, 0.f);
      if (ok) {
        v.x = lp[(size_t)(2 * p) * NPIX];
        v.y = lp[(size_t)(2 * p + 1) * NPIX];
      }
      *reinterpret_cast<float2*>(shl + p * PLSTR + 2 * s) = v;
    }
  }
  __syncthreads();

  // ---- per-thread: pixel px, tap o = 4j + q ----
  const int px = tid >> 2;          // 0..63
  const int q  = tid & 3;           // 0..3
  // per-instruction: 4 q-lanes read 4 CONSECUTIVE dwords (16B run per px)
  const float* wrowq = weights +
      ((size_t)b * NPIX + (size_t)y0 * WW + x0 + px) * WIN2 + q;

  float2 a0 = make_float2(0.f, 0.f);
  float2 a1 = make_float2(0.f, 0.f);
  float2 a2 = make_float2(0.f, 0.f);
  float wsum = 0.f;

#pragma unroll
  for (int j = 0; j < 30; ++j) {
    const int o4 = 4 * j;                 // group base tap (compile-time)
    const int S  = (o4 / WIN) * LABW + (o4 % WIN);   // folded after unroll
    const int Wn = WIN - (o4 % WIN);      // taps of this group in same row
    const float w = wrowq[o4];            // tap o = 4j + q
    wsum += w;
    int li = px + S + q;
    if (Wn < 4) li += (q >= Wn) ? (LABW - WIN) : 0;  // row-wrap correction
    const float2 v0 = *reinterpret_cast<const float2*>(shl + 0 * PLSTR + 2 * li);
    const float2 v1 = *reinterpret_cast<const float2*>(shl + 1 * PLSTR + 2 * li);
    const float2 v2 = *reinterpret_cast<const float2*>(shl + 2 * PLSTR + 2 * li);
    a0.x += w * v0.x; a0.y += w * v0.y;
    a1.x += w * v1.x; a1.y += w * v1.y;
    a2.x += w * v2.x; a2.y += w * v2.y;
  }
  if (q == 0) {                      // tail tap o = 120
    const float w = wrowq[120];
    const int li = px + 10 * LABW + 10;
    wsum += w;
    const float2 v0 = *reinterpret_cast<const float2*>(shl + 0 * PLSTR + 2 * li);
    const float2 v1 = *reinterpret_cast<const float2*>(shl + 1 * PLSTR + 2 * li);
    const float2 v2 = *reinterpret_cast<const float2*>(shl + 2 * PLSTR + 2 * li);
    a0.x += w * v0.x; a0.y += w * v0.y;
    a1.x += w * v1.x; a1.y += w * v1.y;
    a2.x += w * v2.x; a2.y += w * v2.y;
  }

  // ---- reduce the 4 q-lanes (xor 1,2) ----
#pragma unroll
  for (int off = 1; off <= 2; off <<= 1) {
    wsum += __shfl_xor(wsum, off);
    a0.x += __shfl_xor(a0.x, off); a0.y += __shfl_xor(a0.y, off);
    a1.x += __shfl_xor(a1.x, off); a1.y += __shfl_xor(a1.y, off);
    a2.x += __shfl_xor(a2.x, off); a2.y += __shfl_xor(a2.y, off);
  }

  // ---- num/den per pixel (center site = 5*74 + 5) ----
  const int lc = px + 5 * LABW + 5;
  const float2 c0 = *reinterpret_cast<const float2*>(shl + 0 * PLSTR + 2 * lc);
  const float2 c1 = *reinterpret_cast<const float2*>(shl + 1 * PLSTR + 2 * lc);
  const float2 c2 = *reinterpret_cast<const float2*>(shl + 2 * PLSTR + 2 * lc);
  float nv[KCLS] = {c0.x * a0.x, c0.y * a0.y, c1.x * a1.x,
                    c1.y * a1.y, c2.x * a2.x, c2.y * a2.y};
  float dv[KCLS] = {c0.x * wsum, c0.y * wsum, c1.x * wsum,
                    c1.y * wsum, c2.x * wsum, c2.y * wsum};

  // ---- reduce across the 16 pixels of this wave (lane bits 2..5) ----
#pragma unroll
  for (int off = 4; off <= 32; off <<= 1) {
#pragma unroll
    for (int k = 0; k < KCLS; ++k) {
      nv[k] += __shfl_xor(nv[k], off);
      dv[k] += __shfl_xor(dv[k], off);
    }
  }
  const int wave = tid >> 6;
  if ((tid & 63) == 0) {
#pragma unroll
    for (int k = 0; k < KCLS; ++k) {
      shred[wave * 12 + k]     = nv[k];
      shred[wave * 12 + 6 + k] = dv[k];
    }
  }
  __syncthreads();
  if (tid < 12) {
    float s = 0.f;
#pragma unroll
    for (int w = 0; w < 4; ++w) s += shred[w * 12 + tid];
    part[blk * 12 + tid] = s;
  }
}

// ---- final: L = num/den per (b,k); out = K - (1/B) * sum |L| ----
// 8 segments x 32 (b,k)-slots, 32 block-partials each, LDS reduce.
__global__ __launch_bounds__(256) void ncut_final(
    const float* __restrict__ part, float* __restrict__ out) {
  __shared__ float shf[8 * 48];
  const int t   = threadIdx.x;
  const int seg = t >> 5;           // 0..7
  const int bk  = t & 31;           // active < 24
  if (bk < 24) {
    const int b = bk / KCLS;
    const int k = bk - b * KCLS;
    const int r0 = b * 256 + seg * 32;
    float num = 0.f, den = 0.f;
#pragma unroll 4
    for (int i = 0; i < 32; ++i) {
      const float* p = part + (size_t)(r0 + i) * 12;
      num += p[k];
      den += p[6 + k];
    }
    shf[seg * 48 + bk * 2]     = num;
    shf[seg * 48 + bk * 2 + 1] = den;
  }
  __syncthreads();
  float val = 0.f;
  if (t < 24) {
    float n = 0.f, d = 0.f;
#pragma unroll
    for (int s = 0; s < 8; ++s) {
      n += shf[s * 48 + t * 2];
      d += shf[s * 48 + t * 2 + 1];
    }
    val = fabsf(n / d) * (1.0f / BB);
  }
  if (t < 64) {
#pragma unroll
    for (int off = 16; off; off >>= 1) val += __shfl_down(val, off);
    if (t == 0) out[0] = (float)KCLS - val;
  }
}

extern "C" void kernel_launch(void* const* d_in, const int* in_sizes, int n_in,
                              void* d_out, int out_size, void* d_ws, size_t ws_size,
                              hipStream_t stream) {
  const float* labels  = (const float*)d_in[0];
  const float* weights = (const float*)d_in[1];
  float* out  = (float*)d_out;
  float* part = (float*)d_ws;      // 1024 blocks * 12 floats = 49152 B

  ncut_main<<<NBLK, TPB, 0, stream>>>(labels, weights, part);
  ncut_final<<<1, 256, 0, stream>>>(part, out);
}